// Round 14
// baseline (47.243 us; speedup 1.0000x reference)
//
#include <hip/hip_runtime.h>
#include <math.h>

// Problem constants (fixed by the reference)
#define B_   16
#define F_   32
#define NP_  128   // rows per (b,f) panel
#define D_   512
#define P_   16
#define NS   16    // k-steps per wave (K=16 each; s = 2t+p)

typedef __attribute__((ext_vector_type(8)))  short  short8;   // 8 bf16
typedef __attribute__((ext_vector_type(16))) float  floatx16; // 32x32 acc

union Frag { short8 v; unsigned int u[4]; };

__device__ inline unsigned int cvt_pk_bf16(float lo, float hi) {
    unsigned int r;
    asm volatile("v_cvt_pk_bf16_f32 %0, %1, %2" : "=v"(r) : "v"(lo), "v"(hi));
    return r;
}

// 512 blocks (b,f XCD-encoded) x 512 threads = 8 waves = 4 M-tiles x 2
// K-parities (R9's proven decomposition). MAIN LOOP HAS NO LDS, NO DMA, NO
// BARRIERS: each lane streams its A-fragment (8 consecutive floats of its
// own ts row) and B-fragment (8 consecutive floats of its W row) straight
// into VGPRs with a depth-4 register ring and exact per-wave counted vmcnt.
// A wave's lo+hi load pair covers 32 rows x 64B fully (50% per instr, 100%
// per pair via L1). This isolates the global_load_lds DMA+LDS round-trip
// cost that every R9-R13 variant shared.
__global__ __launch_bounds__(512, 4)
void pd_kernel(const float* __restrict__ ts,
               const float* __restrict__ W,
               const float* __restrict__ bias,
               float* __restrict__ out, int T)
{
    __shared__ float smem[NP_ * 33];   // 16.9 KB; EPILOGUE ONLY

    const int tid  = threadIdx.x;
    const int lane = tid & 63;
    const int wave = tid >> 6;       // 0..7
    const int mt   = wave & 3;       // M-tile: rows [32mt, 32mt+32)
    const int p    = wave >> 2;      // k-step parity (0/1)

    // XCD-aware block-id encoding (proven: WRITE_SIZE at ideal ~4.1 MB)
    const int d = blockIdx.x;
    const int b = (d & 7) | ((d >> 8) << 3);
    const int f = (d >> 3) & 31;
    const float* __restrict__ tsb = ts + ((size_t)b * F_ + f) * NP_ * D_;

    // Fragment addressing (byte-identical to verified R9):
    //   A: row = mt*32 + (lane&31), k = s*16 + kh*8 + 0..7   (kh = lane>>5)
    //   B: e   = lane&31,           k = s*16 + kh*8 + 0..7
    const int e_b  = lane & 31;
    const int kh   = lane >> 5;
    const int arow = mt * 32 + e_b;
    const float* __restrict__ aptr = tsb + (size_t)arow * D_ + kh * 8;
    const float* __restrict__ bptr = W + (size_t)e_b * D_ + kh * 8;

    // depth-4 register ring: 16 VMEM ops in flight per wave steady-state
    float4 alo[4], ahi[4], blo[4], bhi[4];
#pragma unroll
    for (int t = 0; t < 4; ++t) {
        const int off = (2 * t + p) * 16;
        alo[t] = *(const float4*)(aptr + off);
        ahi[t] = *(const float4*)(aptr + off + 4);
        blo[t] = *(const float4*)(bptr + off);
        bhi[t] = *(const float4*)(bptr + off + 4);
    }
    __builtin_amdgcn_sched_barrier(0);

    floatx16 acc;
#pragma unroll
    for (int r = 0; r < 16; ++r) acc[r] = 0.f;

    // ---- main loop, fully unrolled. Queue at iter t entry: groups t..t+3
    // (4 ops each). wait vmcnt(12) -> group t arrived; consume; reissue slot.
#pragma unroll
    for (int t = 0; t < NS; ++t) {
        if (t <= 12)      asm volatile("s_waitcnt vmcnt(12)" ::: "memory");
        else if (t == 13) asm volatile("s_waitcnt vmcnt(8)"  ::: "memory");
        else if (t == 14) asm volatile("s_waitcnt vmcnt(4)"  ::: "memory");
        else              asm volatile("s_waitcnt vmcnt(0)"  ::: "memory");
        __builtin_amdgcn_sched_barrier(0);

        const int sl = t & 3;
        Frag a, bb;
        a.u[0]  = cvt_pk_bf16(alo[sl].x, alo[sl].y);
        a.u[1]  = cvt_pk_bf16(alo[sl].z, alo[sl].w);
        a.u[2]  = cvt_pk_bf16(ahi[sl].x, ahi[sl].y);
        a.u[3]  = cvt_pk_bf16(ahi[sl].z, ahi[sl].w);
        bb.u[0] = cvt_pk_bf16(blo[sl].x, blo[sl].y);
        bb.u[1] = cvt_pk_bf16(blo[sl].z, blo[sl].w);
        bb.u[2] = cvt_pk_bf16(bhi[sl].x, bhi[sl].y);
        bb.u[3] = cvt_pk_bf16(bhi[sl].z, bhi[sl].w);

        if (t + 4 < NS) {   // refill freed slot (anti-dep: after the cvts)
            const int off = (2 * (t + 4) + p) * 16;
            alo[sl] = *(const float4*)(aptr + off);
            ahi[sl] = *(const float4*)(aptr + off + 4);
            blo[sl] = *(const float4*)(bptr + off);
            bhi[sl] = *(const float4*)(bptr + off + 4);
        }
        __builtin_amdgcn_sched_barrier(0);

        acc = __builtin_amdgcn_mfma_f32_32x32x16_bf16(a.v, bb.v, acc, 0, 0, 0);
    }

    // ---- epilogue (R9 verbatim): parity merge in LDS raw[n][e], stride 33.
    // C map (m74/m101, verified R9-R13): col=lane&31, row=(r&3)+8*(r>>2)+4*kh.
    if (p == 0) {
#pragma unroll
        for (int r = 0; r < 16; ++r) {
            const int rowl = (r & 3) + 8 * (r >> 2) + 4 * kh;
            smem[(mt * 32 + rowl) * 33 + e_b] = acc[r];
        }
    }
    __syncthreads();
    if (p == 1) {
#pragma unroll
        for (int r = 0; r < 16; ++r) {
            const int rowl = (r & 3) + 8 * (r >> 2) + 4 * kh;
            smem[(mt * 32 + rowl) * 33 + e_b] += acc[r];
        }
    }
    __syncthreads();

    // bias + exp(sigma half): 4096 slots, 8 per thread
#pragma unroll
    for (int jj = 0; jj < 8; ++jj) {
        const int item = tid * 8 + jj;
        const int n = item >> 5;
        const int e = item & 31;
        float v = smem[n * 33 + e] + bias[e];
        if (e >= P_) v = fmaxf(expf(v), 1e-6f);
        smem[n * 33 + e] = v;
    }
    __syncthreads();

    // gather: out[b,t,f] = sum_{n: t-8n in [0,16)} raw[n][.] / cnt
    const int TF = T * F_;
    const size_t halfoff = (size_t)B_ * TF;
    for (int item = tid; item < 2 * T; item += 512) {
        const int half = (item >= T) ? 1 : 0;
        const int t    = item - half * T;
        const int nmax = min(NP_ - 1, t >> 3);
        const int nmin = (t > 8) ? ((t - 8) >> 3) : 0;
        float sum = 0.f;
        const int cnt = nmax - nmin + 1;
        for (int nn = nmin; nn <= nmax; ++nn)
            sum += smem[nn * 33 + (half << 4) + (t - (nn << 3))];
        const float r = (cnt > 0) ? sum / (float)cnt : 0.f;
        out[(size_t)half * halfoff + (size_t)b * TF + (size_t)t * F_ + f] = r;
    }
}

extern "C" void kernel_launch(void* const* d_in, const int* in_sizes, int n_in,
                              void* d_out, int out_size, void* d_ws, size_t ws_size,
                              hipStream_t stream)
{
    const float* ts   = (const float*)d_in[0];
    const float* W    = (const float*)d_in[1];
    const float* bias = (const float*)d_in[2];
    float* out = (float*)d_out;

    // T derived on host from out_size = 2 * B * T * F
    const int T = out_size / (2 * B_ * F_);

    dim3 grid(B_ * F_);   // 512 blocks, one per (b, f), XCD-encoded id
    dim3 block(512);
    pd_kernel<<<grid, block, 0, stream>>>(ts, W, bias, out, T);
}

// Round 15
// 39.542 us; speedup vs baseline: 1.1947x; 1.1947x over previous
//
#include <hip/hip_runtime.h>
#include <math.h>

// Problem constants (fixed by the reference)
#define B_    16
#define F_    32
#define NP_   128   // rows per (b,f) panel
#define D_    512
#define P_    16
#define KC    32            // K-chunk in floats (128 B per row per chunk)
#define NCH   16            // chunks per panel; each = 1 MFMA k-step pair
#define BUFW  (NP_ * KC)    // 4096 floats = 16 KB per ring buffer
#define NRING 8             // 128 KB ring
#define EOFF  (NRING * BUFW)

typedef __attribute__((ext_vector_type(8)))  short  short8;   // 8 bf16
typedef __attribute__((ext_vector_type(16))) float  floatx16; // 32x32 acc

union Frag { short8 v; unsigned int u[4]; };

__device__ inline unsigned int cvt_pk_bf16(float lo, float hi) {
    unsigned int r;
    asm volatile("v_cvt_pk_bf16_f32 %0, %1, %2" : "=v"(r) : "v"(lo), "v"(hi));
    return r;
}

// epilogue barrier that does NOT drain vmcnt (keeps next panel's DMA in flight)
#define EBAR asm volatile("s_waitcnt lgkmcnt(0)\n\ts_barrier" ::: "memory")

// 256 blocks (1 per CU, single-round dispatch) x 512 threads = 8 waves =
// 4 M-tiles(32 rows) x 2 K-parities. Each block processes TWO ADJACENT
// panels (b, 2fp) and (b, 2fp+1) = 512 KB contiguous, with one continuous
// deep pipeline: ring of 8 LDS buffers, prefetch depth 7, one barrier per
// chunk. During panel0's chunks 9..15 we stage panel1's chunks 0..6, so
// outstanding DMA stays at exactly 14 ops (vmcnt(12)) across the boundary —
// the stream never drains. B (W) preloaded once for both panels.
__global__ __launch_bounds__(512, 4)
void pd_kernel(const float* __restrict__ ts,
               const float* __restrict__ W,
               const float* __restrict__ bias,
               float* __restrict__ out, int T)
{
    __shared__ float smem[EOFF + NP_ * 33];   // 128 KB ring + 16.5 KB epilogue

    const int tid  = threadIdx.x;
    const int lane = tid & 63;
    const int wave = tid >> 6;       // 0..7
    const int mt   = wave & 3;       // M-tile: rows [32mt, 32mt+32)
    const int p    = wave >> 2;      // k-step parity (0/1)

    // 256-block XCD encoding: xcd = d&7 carries b&7; 2 b's per XCD; the two
    // panels of a block are adjacent f's of one b (contiguous 512 KB).
    const int d  = blockIdx.x;
    const int b  = (d & 7) | (((d >> 7) & 1) << 3);
    const int fp = (d >> 3) & 15;
    const float* __restrict__ tsb0 = ts + ((size_t)(b * F_ + 2 * fp) * NP_) * D_;
    const float* __restrict__ tsb1 = tsb0 + (size_t)NP_ * D_;

    // Stage chunk cc of panel base into ring slot cc&7 (16%8==0 -> continuous
    // numbering across panels). slot(r,ql) holds global quad ql^(r&7)
    // (bijective per row; proven conflict-free family, R5/R6).
    auto STAGE = [&](const float* base, int cc) {
#pragma unroll
        for (int it = 0; it < 2; ++it) {
            const int slot = it * 512 + tid;   // 0..1023 (128 rows x 8 quads)
            const int r2 = slot >> 3;
            const int qg = (slot & 7) ^ (r2 & 7);
            const float* src = base + r2 * D_ + cc * KC + (qg << 2);
            float* dst = smem + (cc & 7) * BUFW + (slot << 2);
            __builtin_amdgcn_global_load_lds(
                (const __attribute__((address_space(1))) unsigned int*)src,
                (__attribute__((address_space(3))) unsigned int*)dst,
                16, 0, 0);
        }
    };

    // ---- B preload ONCE (both panels share W): wave's 16 k-steps s = 2c+p.
    const int e_b = lane & 31;
    const int kh  = lane >> 5;
    Frag bf[NCH];
    {
        const float* wb = W + (size_t)e_b * D_ + kh * 8;
#pragma unroll
        for (int c = 0; c < NCH; ++c) {
            const int k = c * 32 + p * 16;
            const float4 lo = *(const float4*)(wb + k);
            const float4 hi = *(const float4*)(wb + k + 4);
            bf[c].u[0] = cvt_pk_bf16(lo.x, lo.y);
            bf[c].u[1] = cvt_pk_bf16(lo.z, lo.w);
            bf[c].u[2] = cvt_pk_bf16(hi.x, hi.y);
            bf[c].u[3] = cvt_pk_bf16(hi.z, hi.w);
        }
    }
    __builtin_amdgcn_sched_barrier(0);   // all B consumed before stages issue

    // ---- prologue: fill 7 of 8 ring slots (14 DMA ops in flight)
#pragma unroll
    for (int c = 0; c < 7; ++c) STAGE(tsb0, c);
    __builtin_amdgcn_sched_barrier(0);

    // A-frag addressing (R11 verbatim): row = mt*32 + (lane&31)
    const int ldsrow = mt * 32 + (lane & 31);
    const int sw8    = ldsrow & 7;
    const int aq     = p * 4 + kh * 2;

    const int TF = T * F_;
    const size_t halfoff = (size_t)B_ * TF;
    float* const E = smem + EOFF;

    // ---- two panels, one continuous pipeline
#pragma unroll
    for (int q = 0; q < 2; ++q) {
        const float* __restrict__ tscur = q ? tsb1 : tsb0;

        floatx16 acc;
#pragma unroll
        for (int r = 0; r < 16; ++r) acc[r] = 0.f;

#pragma unroll
        for (int c = 0; c < NCH; ++c) {
            // waits: panel0 holds 14 ops outstanding at every iter (cross-
            // panel staging keeps the count constant); panel1 tails off.
            if (q == 0 || c <= 9)
                asm volatile("s_waitcnt vmcnt(12)\n\ts_barrier" ::: "memory");
            else if (c == 10)
                asm volatile("s_waitcnt vmcnt(10)\n\ts_barrier" ::: "memory");
            else if (c == 11)
                asm volatile("s_waitcnt vmcnt(8)\n\ts_barrier" ::: "memory");
            else if (c == 12)
                asm volatile("s_waitcnt vmcnt(6)\n\ts_barrier" ::: "memory");
            else if (c == 13)
                asm volatile("s_waitcnt vmcnt(4)\n\ts_barrier" ::: "memory");
            else if (c == 14)
                asm volatile("s_waitcnt vmcnt(2)\n\ts_barrier" ::: "memory");
            else
                asm volatile("s_waitcnt vmcnt(0)\n\ts_barrier" ::: "memory");
            __builtin_amdgcn_sched_barrier(0);

            if (q == 0) {
                if (c <= 8) STAGE(tsb0, c + 7);   // panel0 chunks 7..15
                else        STAGE(tsb1, c - 9);   // panel1 chunks 0..6
            } else {
                if (c <= 8) STAGE(tsb1, c + 7);   // panel1 chunks 7..15
            }
            __builtin_amdgcn_sched_barrier(0);

            // compute(c): ring slot c&7, swizzled ds_read_b128 x2 -> MFMA
            const float* rowp = smem + (c & 7) * BUFW + ldsrow * KC;
            const float4 lo = *(const float4*)(rowp + ((aq ^ sw8) << 2));
            const float4 hi = *(const float4*)(rowp + (((aq + 1) ^ sw8) << 2));
            Frag a;
            a.u[0] = cvt_pk_bf16(lo.x, lo.y);
            a.u[1] = cvt_pk_bf16(lo.z, lo.w);
            a.u[2] = cvt_pk_bf16(hi.x, hi.y);
            a.u[3] = cvt_pk_bf16(hi.z, hi.w);
            acc = __builtin_amdgcn_mfma_f32_32x32x16_bf16(a.v, bf[c].v, acc, 0, 0, 0);
        }

        // ---- epilogue for panel q (f = 2fp+q). RAW barriers only: must not
        // drain the in-flight panel1 DMA. E region disjoint from ring.
        // C map (m74/m101, verified R9+): col=lane&31, row=(r&3)+8*(r>>2)+4*kh.
        const int f = 2 * fp + q;
        if (p == 0) {
#pragma unroll
            for (int r = 0; r < 16; ++r) {
                const int rowl = (r & 3) + 8 * (r >> 2) + 4 * kh;
                E[(mt * 32 + rowl) * 33 + e_b] = acc[r];
            }
        }
        EBAR;
        if (p == 1) {
#pragma unroll
            for (int r = 0; r < 16; ++r) {
                const int rowl = (r & 3) + 8 * (r >> 2) + 4 * kh;
                E[(mt * 32 + rowl) * 33 + e_b] += acc[r];
            }
        }
        EBAR;

        // bias + exp(sigma half): 4096 slots, 8 per thread
#pragma unroll
        for (int jj = 0; jj < 8; ++jj) {
            const int item = tid * 8 + jj;
            const int n = item >> 5;
            const int e = item & 31;
            float v = E[n * 33 + e] + bias[e];
            if (e >= P_) v = fmaxf(expf(v), 1e-6f);
            E[n * 33 + e] = v;
        }
        EBAR;

        // gather: out[b,t,f] = sum_{n: t-8n in [0,16)} raw[n][.] / cnt
        for (int item = tid; item < 2 * T; item += 512) {
            const int half = (item >= T) ? 1 : 0;
            const int t    = item - half * T;
            const int nmax = min(NP_ - 1, t >> 3);
            const int nmin = (t > 8) ? ((t - 8) >> 3) : 0;
            float sum = 0.f;
            const int cnt = nmax - nmin + 1;
            for (int nn = nmin; nn <= nmax; ++nn)
                sum += E[nn * 33 + (half << 4) + (t - (nn << 3))];
            const float r = (cnt > 0) ? sum / (float)cnt : 0.f;
            out[(size_t)half * halfoff + (size_t)b * TF + (size_t)t * F_ + f] = r;
        }
        // no extra barrier needed before panel1: its 16 loop barriers order
        // all waves' gather reads ahead of the next epilogue's E writes.
    }
}

extern "C" void kernel_launch(void* const* d_in, const int* in_sizes, int n_in,
                              void* d_out, int out_size, void* d_ws, size_t ws_size,
                              hipStream_t stream)
{
    const float* ts   = (const float*)d_in[0];
    const float* W    = (const float*)d_in[1];
    const float* bias = (const float*)d_in[2];
    float* out = (float*)d_out;

    // T derived on host from out_size = 2 * B * T * F
    const int T = out_size / (2 * B_ * F_);

    dim3 grid(B_ * F_ / 2);   // 256 blocks: 1 per CU, 2 adjacent panels each
    dim3 block(512);
    pd_kernel<<<grid, block, 0, stream>>>(ts, W, bias, out, T);
}

// Round 16
// 37.157 us; speedup vs baseline: 1.2714x; 1.0642x over previous
//
#include <hip/hip_runtime.h>
#include <math.h>

// Problem constants (fixed by the reference)
#define B_    16
#define F_    32
#define NP_   128   // rows per (b,f) panel
#define D_    512
#define P_    16
#define KC    32            // K-chunk in floats (128 B per row per chunk)
#define NCH   16            // chunks per panel; each = 1 MFMA k-step pair
#define BUFW  (NP_ * KC)    // 4096 floats = 16 KB per ring buffer
#define NRING 8             // 128 KB ring
#define EOFF  (NRING * BUFW)

typedef __attribute__((ext_vector_type(8)))  short  short8;   // 8 bf16
typedef __attribute__((ext_vector_type(16))) float  floatx16; // 32x32 acc

union Frag { short8 v; unsigned int u[4]; };

__device__ inline unsigned int cvt_pk_bf16(float lo, float hi) {
    unsigned int r;
    asm volatile("v_cvt_pk_bf16_f32 %0, %1, %2" : "=v"(r) : "v"(lo), "v"(hi));
    return r;
}

// epilogue barrier that does NOT drain vmcnt (keeps DMA in flight)
#define EBAR asm volatile("s_waitcnt lgkmcnt(0)\n\ts_barrier" ::: "memory")

// 256 blocks (1/CU, single-round) x 512 threads = 8 waves = 4 M-tiles x 2
// K-parities. Two adjacent panels per block, one continuous deep pipeline
// (ring of 8, depth 7, counted vmcnt). R16 changes vs R15:
//  (1) STAGE(0),STAGE(1) issue BEFORE the B-preload -> B's load latency
//      overlaps the first 32 KB of DMA instead of serially preceding it.
//  (2) Panel-0's epilogue is folded into panel-1's loop as per-iteration
//      phases (merge/bias/gather quarters), ordered by the loop's own
//      barriers (with lgkmcnt(0) added) -> DMA issue never pauses.
__global__ __launch_bounds__(512, 2)
void pd_kernel(const float* __restrict__ ts,
               const float* __restrict__ W,
               const float* __restrict__ bias,
               float* __restrict__ out, int T)
{
    __shared__ float smem[EOFF + NP_ * 33];   // 128 KB ring + 16.5 KB epilogue

    const int tid  = threadIdx.x;
    const int lane = tid & 63;
    const int wave = tid >> 6;       // 0..7
    const int mt   = wave & 3;       // M-tile: rows [32mt, 32mt+32)
    const int p    = wave >> 2;      // k-step parity (0/1)

    // 256-block XCD encoding: xcd = d&7 carries b&7; panels are adjacent f's
    const int d  = blockIdx.x;
    const int b  = (d & 7) | (((d >> 7) & 1) << 3);
    const int fp = (d >> 3) & 15;
    const float* __restrict__ tsb0 = ts + ((size_t)(b * F_ + 2 * fp) * NP_) * D_;
    const float* __restrict__ tsb1 = tsb0 + (size_t)NP_ * D_;

    // Stage chunk cc into ring slot cc&7. slot(r,ql) holds global quad
    // ql^(r&7) (bijective per row; proven conflict-free family).
    auto STAGE = [&](const float* base, int cc) {
#pragma unroll
        for (int it = 0; it < 2; ++it) {
            const int slot = it * 512 + tid;   // 0..1023 (128 rows x 8 quads)
            const int r2 = slot >> 3;
            const int qg = (slot & 7) ^ (r2 & 7);
            const float* src = base + r2 * D_ + cc * KC + (qg << 2);
            float* dst = smem + (cc & 7) * BUFW + (slot << 2);
            __builtin_amdgcn_global_load_lds(
                (const __attribute__((address_space(1))) unsigned int*)src,
                (__attribute__((address_space(3))) unsigned int*)dst,
                16, 0, 0);
        }
    };

    // ---- (1) start DMA immediately
    STAGE(tsb0, 0);
    STAGE(tsb0, 1);
    __builtin_amdgcn_sched_barrier(0);

    // ---- B preload ONCE (both panels share W); its waits overlap stages 0-1
    const int e_b = lane & 31;
    const int kh  = lane >> 5;
    Frag bf[NCH];
    {
        const float* wb = W + (size_t)e_b * D_ + kh * 8;
#pragma unroll
        for (int c = 0; c < NCH; ++c) {
            const int k = c * 32 + p * 16;
            const float4 lo = *(const float4*)(wb + k);
            const float4 hi = *(const float4*)(wb + k + 4);
            bf[c].u[0] = cvt_pk_bf16(lo.x, lo.y);
            bf[c].u[1] = cvt_pk_bf16(lo.z, lo.w);
            bf[c].u[2] = cvt_pk_bf16(hi.x, hi.y);
            bf[c].u[3] = cvt_pk_bf16(hi.z, hi.w);
        }
    }
    __builtin_amdgcn_sched_barrier(0);

    // ---- rest of the ring prologue (chunks 2..6 -> 10 ops outstanding)
#pragma unroll
    for (int c = 2; c < 7; ++c) STAGE(tsb0, c);
    __builtin_amdgcn_sched_barrier(0);

    // A-frag addressing: row = mt*32 + (lane&31)
    const int ldsrow = mt * 32 + (lane & 31);
    const int sw8    = ldsrow & 7;
    const int aq     = p * 4 + kh * 2;

    const int TF = T * F_;
    const size_t halfoff = (size_t)B_ * TF;
    float* const E = smem + EOFF;

    // compute one chunk from ring slot c&7 into acc
    auto COMPUTE = [&](int c, floatx16& acc) {
        const float* rowp = smem + (c & 7) * BUFW + ldsrow * KC;
        const float4 lo = *(const float4*)(rowp + ((aq ^ sw8) << 2));
        const float4 hi = *(const float4*)(rowp + (((aq + 1) ^ sw8) << 2));
        Frag a;
        a.u[0] = cvt_pk_bf16(lo.x, lo.y);
        a.u[1] = cvt_pk_bf16(lo.z, lo.w);
        a.u[2] = cvt_pk_bf16(hi.x, hi.y);
        a.u[3] = cvt_pk_bf16(hi.z, hi.w);
        acc = __builtin_amdgcn_mfma_f32_32x32x16_bf16(a.v, bf[c].v, acc, 0, 0, 0);
    };

    floatx16 accA, accB;
#pragma unroll
    for (int r = 0; r < 16; ++r) { accA[r] = 0.f; accB[r] = 0.f; }

    // ---- panel 0 loop: steady vmcnt(12); stages roll into panel 1 chunks
#pragma unroll
    for (int c = 0; c < NCH; ++c) {
        asm volatile("s_waitcnt vmcnt(12)\n\ts_barrier" ::: "memory");
        __builtin_amdgcn_sched_barrier(0);
        if (c <= 8) STAGE(tsb0, c + 7);
        else        STAGE(tsb1, c - 9);
        __builtin_amdgcn_sched_barrier(0);
        COMPUTE(c, accA);
    }

    // ---- panel 1 loop with panel-0 epilogue folded in as phases.
    // C map (m74/m101, verified R9+): col=lane&31, row=(r&3)+8*(r>>2)+4*kh.
    const int f0 = 2 * fp;
    const int QT = (2 * T + 3) / 4;   // gather quarter size
#pragma unroll
    for (int c = 0; c < NCH; ++c) {
        // lgkmcnt(0) on phase iters: orders E ds-writes across the barrier
        if (c <= 9)
            asm volatile("s_waitcnt vmcnt(12) lgkmcnt(0)\n\ts_barrier" ::: "memory");
        else if (c == 10)
            asm volatile("s_waitcnt vmcnt(10)\n\ts_barrier" ::: "memory");
        else if (c == 11)
            asm volatile("s_waitcnt vmcnt(8)\n\ts_barrier" ::: "memory");
        else if (c == 12)
            asm volatile("s_waitcnt vmcnt(6)\n\ts_barrier" ::: "memory");
        else if (c == 13)
            asm volatile("s_waitcnt vmcnt(4)\n\ts_barrier" ::: "memory");
        else if (c == 14)
            asm volatile("s_waitcnt vmcnt(2)\n\ts_barrier" ::: "memory");
        else
            asm volatile("s_waitcnt vmcnt(0)\n\ts_barrier" ::: "memory");
        __builtin_amdgcn_sched_barrier(0);

        if (c <= 8) STAGE(tsb1, c + 7);
        __builtin_amdgcn_sched_barrier(0);

        // ---- panel-0 epilogue phase (barrier-separated by the loop itself)
        if (c == 0) {                       // p0 merge write
            if (p == 0) {
#pragma unroll
                for (int r = 0; r < 16; ++r) {
                    const int rowl = (r & 3) + 8 * (r >> 2) + 4 * kh;
                    E[(mt * 32 + rowl) * 33 + e_b] = accA[r];
                }
            }
        } else if (c == 1) {                // p1 merge add
            if (p == 1) {
#pragma unroll
                for (int r = 0; r < 16; ++r) {
                    const int rowl = (r & 3) + 8 * (r >> 2) + 4 * kh;
                    E[(mt * 32 + rowl) * 33 + e_b] += accA[r];
                }
            }
        } else if (c == 2) {                // bias + exp (sigma half)
#pragma unroll
            for (int jj = 0; jj < 8; ++jj) {
                const int item = tid * 8 + jj;
                const int n = item >> 5;
                const int e = item & 31;
                float v = E[n * 33 + e] + bias[e];
                if (e >= P_) v = fmaxf(expf(v), 1e-6f);
                E[n * 33 + e] = v;
            }
        } else if (c >= 3 && c <= 6) {      // gather quarter (c-3) -> out[f0]
            const int g  = c - 3;
            const int hi = min((g + 1) * QT, 2 * T);
            for (int item = g * QT + tid; item < hi; item += 512) {
                const int half = (item >= T) ? 1 : 0;
                const int t    = item - half * T;
                const int nmax = min(NP_ - 1, t >> 3);
                const int nmin = (t > 8) ? ((t - 8) >> 3) : 0;
                float sum = 0.f;
                const int cnt = nmax - nmin + 1;
                for (int nn = nmin; nn <= nmax; ++nn)
                    sum += E[nn * 33 + (half << 4) + (t - (nn << 3))];
                const float r = (cnt > 0) ? sum / (float)cnt : 0.f;
                out[(size_t)half * halfoff + (size_t)b * TF + (size_t)t * F_ + f0] = r;
            }
        }

        COMPUTE(c, accB);
    }

    // ---- panel-1 epilogue (tail; EBAR-sequenced, R15 verbatim)
    const int f1 = 2 * fp + 1;
    if (p == 0) {
#pragma unroll
        for (int r = 0; r < 16; ++r) {
            const int rowl = (r & 3) + 8 * (r >> 2) + 4 * kh;
            E[(mt * 32 + rowl) * 33 + e_b] = accB[r];
        }
    }
    EBAR;
    if (p == 1) {
#pragma unroll
        for (int r = 0; r < 16; ++r) {
            const int rowl = (r & 3) + 8 * (r >> 2) + 4 * kh;
            E[(mt * 32 + rowl) * 33 + e_b] += accB[r];
        }
    }
    EBAR;
#pragma unroll
    for (int jj = 0; jj < 8; ++jj) {
        const int item = tid * 8 + jj;
        const int n = item >> 5;
        const int e = item & 31;
        float v = E[n * 33 + e] + bias[e];
        if (e >= P_) v = fmaxf(expf(v), 1e-6f);
        E[n * 33 + e] = v;
    }
    EBAR;
    for (int item = tid; item < 2 * T; item += 512) {
        const int half = (item >= T) ? 1 : 0;
        const int t    = item - half * T;
        const int nmax = min(NP_ - 1, t >> 3);
        const int nmin = (t > 8) ? ((t - 8) >> 3) : 0;
        float sum = 0.f;
        const int cnt = nmax - nmin + 1;
        for (int nn = nmin; nn <= nmax; ++nn)
            sum += E[nn * 33 + (half << 4) + (t - (nn << 3))];
        const float r = (cnt > 0) ? sum / (float)cnt : 0.f;
        out[(size_t)half * halfoff + (size_t)b * TF + (size_t)t * F_ + f1] = r;
    }
}

extern "C" void kernel_launch(void* const* d_in, const int* in_sizes, int n_in,
                              void* d_out, int out_size, void* d_ws, size_t ws_size,
                              hipStream_t stream)
{
    const float* ts   = (const float*)d_in[0];
    const float* W    = (const float*)d_in[1];
    const float* bias = (const float*)d_in[2];
    float* out = (float*)d_out;

    // T derived on host from out_size = 2 * B * T * F
    const int T = out_size / (2 * B_ * F_);

    dim3 grid(B_ * F_ / 2);   // 256 blocks: 1 per CU, 2 adjacent panels each
    dim3 block(512);
    pd_kernel<<<grid, block, 0, stream>>>(ts, W, bias, out, T);
}

// Round 17
// 36.691 us; speedup vs baseline: 1.2876x; 1.0127x over previous
//
#include <hip/hip_runtime.h>
#include <math.h>

// Problem constants (fixed by the reference)
#define B_    16
#define F_    32
#define NP_   128   // rows per (b,f) panel
#define D_    512
#define P_    16
#define KC    64            // K-chunk in floats (256 B per row per chunk)
#define NCH   8             // chunks per panel; each = 4 MFMA k-steps (2/wave)
#define BUFW  (NP_ * KC)    // 8192 floats = 32 KB per ring buffer
#define NRING 4             // 128 KB ring
#define EOFF  (NRING * BUFW)

typedef __attribute__((ext_vector_type(8)))  short  short8;   // 8 bf16
typedef __attribute__((ext_vector_type(16))) float  floatx16; // 32x32 acc

union Frag { short8 v; unsigned int u[4]; };

__device__ inline unsigned int cvt_pk_bf16(float lo, float hi) {
    unsigned int r;
    asm volatile("v_cvt_pk_bf16_f32 %0, %1, %2" : "=v"(r) : "v"(lo), "v"(hi));
    return r;
}

// epilogue barrier that does NOT drain vmcnt
#define EBAR asm volatile("s_waitcnt lgkmcnt(0)\n\ts_barrier" ::: "memory")

// 256 blocks (1/CU, single-round) x 512 threads = 8 waves = 4 M-tiles x 2
// K-parities. Two adjacent panels per block, one continuous pipeline.
// R17 vs R16: KC=64 (half the barrier-steps: 16 total), ring 4x32KB depth-3
// (wait vmcnt(8) -> barrier -> STAGE(c+3) -> compute), and the merge-add/
// bias/exp passes fused into ONE pass (p1 threads cover all slots).
__global__ __launch_bounds__(512, 2)
void pd_kernel(const float* __restrict__ ts,
               const float* __restrict__ W,
               const float* __restrict__ bias,
               float* __restrict__ out, int T)
{
    __shared__ float smem[EOFF + NP_ * 33];   // 128 KB ring + 16.5 KB epilogue

    const int tid  = threadIdx.x;
    const int lane = tid & 63;
    const int wave = tid >> 6;       // 0..7
    const int mt   = wave & 3;       // M-tile: rows [32mt, 32mt+32)
    const int p    = wave >> 2;      // k-step parity (0/1)

    // 256-block XCD encoding: xcd = d&7 carries b&7; panels are adjacent f's
    const int d  = blockIdx.x;
    const int b  = (d & 7) | (((d >> 7) & 1) << 3);
    const int fp = (d >> 3) & 15;
    const float* __restrict__ tsb0 = ts + ((size_t)(b * F_ + 2 * fp) * NP_) * D_;
    const float* __restrict__ tsb1 = tsb0 + (size_t)NP_ * D_;

    // Stage chunk cc into ring slot cc&3: 2048 16B-slots (128 rows x 16
    // quads), 4 wave-instrs/wave. slot(r,ql) holds global quad ql^(r&15)
    // (bijective per row; R5-verified conflict-free 16-quad family).
    auto STAGE = [&](const float* base, int cc) {
#pragma unroll
        for (int it = 0; it < 4; ++it) {
            const int slot = it * 512 + tid;
            const int r2 = slot >> 4;
            const int qg = (slot & 15) ^ (r2 & 15);
            const float* src = base + r2 * D_ + cc * KC + (qg << 2);
            float* dst = smem + (cc & 3) * BUFW + (slot << 2);
            __builtin_amdgcn_global_load_lds(
                (const __attribute__((address_space(1))) unsigned int*)src,
                (__attribute__((address_space(3))) unsigned int*)dst,
                16, 0, 0);
        }
    };

    // ---- start DMA immediately (8 ops)
    STAGE(tsb0, 0);
    STAGE(tsb0, 1);
    __builtin_amdgcn_sched_barrier(0);

    // ---- B preload ONCE (shared by both panels); overlaps stages 0-1.
    // Wave's 16 k-steps: s = 4c + p + 2j (c=0..7, j=0..1).
    const int e_b = lane & 31;
    const int kh  = lane >> 5;
    Frag bf[NCH][2];
    {
        const float* wb = W + (size_t)e_b * D_ + kh * 8;
#pragma unroll
        for (int c = 0; c < NCH; ++c)
#pragma unroll
            for (int j = 0; j < 2; ++j) {
                const int k = (4 * c + p + 2 * j) * 16;
                const float4 lo = *(const float4*)(wb + k);
                const float4 hi = *(const float4*)(wb + k + 4);
                bf[c][j].u[0] = cvt_pk_bf16(lo.x, lo.y);
                bf[c][j].u[1] = cvt_pk_bf16(lo.z, lo.w);
                bf[c][j].u[2] = cvt_pk_bf16(hi.x, hi.y);
                bf[c][j].u[3] = cvt_pk_bf16(hi.z, hi.w);
            }
    }
    __builtin_amdgcn_sched_barrier(0);

    STAGE(tsb0, 2);                  // 12 ops outstanding entering the loop
    __builtin_amdgcn_sched_barrier(0);

    // A-frag addressing: row = mt*32 + (lane&31); 16 quads/row, XOR row&15
    const int ldsrow = mt * 32 + (lane & 31);
    const int sw16   = ldsrow & 15;
    const int aq     = p * 4 + kh * 2;   // quad of k-step j=0 (j=1: +8)

    const int TF = T * F_;
    const size_t halfoff = (size_t)B_ * TF;
    float* const E = smem + EOFF;

    auto COMPUTE = [&](int c, floatx16& acc) {
        const float* rowp = smem + (c & 3) * BUFW + ldsrow * KC;
#pragma unroll
        for (int j = 0; j < 2; ++j) {
            const int q0 = aq + j * 8;
            const float4 lo = *(const float4*)(rowp + ((q0 ^ sw16) << 2));
            const float4 hi = *(const float4*)(rowp + (((q0 + 1) ^ sw16) << 2));
            Frag a;
            a.u[0] = cvt_pk_bf16(lo.x, lo.y);
            a.u[1] = cvt_pk_bf16(lo.z, lo.w);
            a.u[2] = cvt_pk_bf16(hi.x, hi.y);
            a.u[3] = cvt_pk_bf16(hi.z, hi.w);
            acc = __builtin_amdgcn_mfma_f32_32x32x16_bf16(a.v, bf[c][j].v, acc, 0, 0, 0);
        }
    };

    floatx16 accA, accB;
#pragma unroll
    for (int r = 0; r < 16; ++r) { accA[r] = 0.f; accB[r] = 0.f; }

    // ---- panel 0 loop: wait chunk c (vmcnt(8)) -> barrier -> STAGE(c+3)
#pragma unroll
    for (int c = 0; c < NCH; ++c) {
        asm volatile("s_waitcnt vmcnt(8)\n\ts_barrier" ::: "memory");
        __builtin_amdgcn_sched_barrier(0);
        if (c <= 4) STAGE(tsb0, c + 3);
        else        STAGE(tsb1, c - 5);   // panel1 chunks 0..2
        __builtin_amdgcn_sched_barrier(0);
        COMPUTE(c, accA);
    }

    // ---- panel 1 loop with panel-0 epilogue folded in as phases.
    // C map (m74/m101, verified R9+): col=lane&31, row=(r&3)+8*(r>>2)+4*kh.
    const int f0 = 2 * fp;
    const int QT = (2 * T + 3) / 4;   // gather quarter size
#pragma unroll
    for (int c = 0; c < NCH; ++c) {
        if (c <= 4)
            asm volatile("s_waitcnt vmcnt(8) lgkmcnt(0)\n\ts_barrier" ::: "memory");
        else if (c == 5)
            asm volatile("s_waitcnt vmcnt(8) lgkmcnt(0)\n\ts_barrier" ::: "memory");
        else if (c == 6)
            asm volatile("s_waitcnt vmcnt(4) lgkmcnt(0)\n\ts_barrier" ::: "memory");
        else
            asm volatile("s_waitcnt vmcnt(0) lgkmcnt(0)\n\ts_barrier" ::: "memory");
        __builtin_amdgcn_sched_barrier(0);

        if (c <= 4) STAGE(tsb1, c + 3);
        __builtin_amdgcn_sched_barrier(0);

        // panel-0 epilogue phase (ordered by the loop's own barriers)
        if (c == 0) {                       // p0 partial write
            if (p == 0) {
#pragma unroll
                for (int r = 0; r < 16; ++r) {
                    const int rowl = (r & 3) + 8 * (r >> 2) + 4 * kh;
                    E[(mt * 32 + rowl) * 33 + e_b] = accA[r];
                }
            }
        } else if (c == 1) {                // p1: add + bias + exp FUSED
            if (p == 1) {
#pragma unroll
                for (int r = 0; r < 16; ++r) {
                    const int rowl = (r & 3) + 8 * (r >> 2) + 4 * kh;
                    float v = E[(mt * 32 + rowl) * 33 + e_b] + accA[r] + bias[e_b];
                    if (e_b >= P_) v = fmaxf(expf(v), 1e-6f);
                    E[(mt * 32 + rowl) * 33 + e_b] = v;
                }
            }
        } else if (c >= 2 && c <= 5) {      // gather quarter (c-2) -> out[f0]
            const int g  = c - 2;
            const int hi = min((g + 1) * QT, 2 * T);
            for (int item = g * QT + tid; item < hi; item += 512) {
                const int half = (item >= T) ? 1 : 0;
                const int t    = item - half * T;
                const int nmax = min(NP_ - 1, t >> 3);
                const int nmin = (t > 8) ? ((t - 8) >> 3) : 0;
                float sum = 0.f;
                const int cnt = nmax - nmin + 1;
                for (int nn = nmin; nn <= nmax; ++nn)
                    sum += E[nn * 33 + (half << 4) + (t - (nn << 3))];
                const float r = (cnt > 0) ? sum / (float)cnt : 0.f;
                out[(size_t)half * halfoff + (size_t)b * TF + (size_t)t * F_ + f0] = r;
            }
        }

        COMPUTE(c, accB);
    }

    // ---- panel-1 tail epilogue (2 LDS passes, fused add/bias/exp)
    const int f1 = 2 * fp + 1;
    if (p == 0) {
#pragma unroll
        for (int r = 0; r < 16; ++r) {
            const int rowl = (r & 3) + 8 * (r >> 2) + 4 * kh;
            E[(mt * 32 + rowl) * 33 + e_b] = accB[r];
        }
    }
    EBAR;
    if (p == 1) {
#pragma unroll
        for (int r = 0; r < 16; ++r) {
            const int rowl = (r & 3) + 8 * (r >> 2) + 4 * kh;
            float v = E[(mt * 32 + rowl) * 33 + e_b] + accB[r] + bias[e_b];
            if (e_b >= P_) v = fmaxf(expf(v), 1e-6f);
            E[(mt * 32 + rowl) * 33 + e_b] = v;
        }
    }
    EBAR;
    for (int item = tid; item < 2 * T; item += 512) {
        const int half = (item >= T) ? 1 : 0;
        const int t    = item - half * T;
        const int nmax = min(NP_ - 1, t >> 3);
        const int nmin = (t > 8) ? ((t - 8) >> 3) : 0;
        float sum = 0.f;
        const int cnt = nmax - nmin + 1;
        for (int nn = nmin; nn <= nmax; ++nn)
            sum += E[nn * 33 + (half << 4) + (t - (nn << 3))];
        const float r = (cnt > 0) ? sum / (float)cnt : 0.f;
        out[(size_t)half * halfoff + (size_t)b * TF + (size_t)t * F_ + f1] = r;
    }
}

extern "C" void kernel_launch(void* const* d_in, const int* in_sizes, int n_in,
                              void* d_out, int out_size, void* d_ws, size_t ws_size,
                              hipStream_t stream)
{
    const float* ts   = (const float*)d_in[0];
    const float* W    = (const float*)d_in[1];
    const float* bias = (const float*)d_in[2];
    float* out = (float*)d_out;

    // T derived on host from out_size = 2 * B * T * F
    const int T = out_size / (2 * B_ * F_);

    dim3 grid(B_ * F_ / 2);   // 256 blocks: 1 per CU, 2 adjacent panels each
    dim3 block(512);
    pd_kernel<<<grid, block, 0, stream>>>(ts, W, bias, out, T);
}

// Round 18
// 36.192 us; speedup vs baseline: 1.3053x; 1.0138x over previous
//
#include <hip/hip_runtime.h>
#include <math.h>

// Problem constants (fixed by the reference)
#define B_    16
#define F_    32
#define NP_   128   // rows per (b,f) panel
#define D_    512
#define P_    16
#define KC    64            // fp32 k-values per chunk-step
#define NCHT  16            // total chunk-steps (2 panels x 8)
#define SLOTF 4096          // floats per ring slot (16 KB; holds bf16 chunk)
#define EOFFF (4 * SLOTF)   // ring = 4 slots = 64 KB; E after

typedef __attribute__((ext_vector_type(8)))  short  short8;   // 8 bf16
typedef __attribute__((ext_vector_type(16))) float  floatx16; // 32x32 acc

union Frag { short8 v; unsigned int u[4]; };

__device__ inline unsigned int cvt_pk_bf16(float lo, float hi) {
    unsigned int r;
    asm volatile("v_cvt_pk_bf16_f32 %0, %1, %2" : "=v"(r) : "v"(lo), "v"(hi));
    return r;
}

#define SB  __builtin_amdgcn_sched_barrier(0)
#define BAR asm volatile("s_waitcnt lgkmcnt(0)\n\ts_barrier" ::: "memory")

// 256 blocks (1/CU) x 512 threads = 8 waves = 4 M-tiles x 2 K-parities.
// R18: staging switched from the global_load_lds DMA engine to REG-STAGING
// (plain coalesced loads -> cvt to bf16 -> swizzled ds_write). Tests whether
// the DMA path's ~16.5 GB/s/CU was the wall (m13: plain loads do 24.6).
// Ring 4 x 16 KB bf16; loads 3 steps ahead (compiler-counted vmcnt), write
// 1 step ahead, ONE barrier per chunk-step; phases + fused epilogue kept.
__global__ __launch_bounds__(512, 2)
void pd_kernel(const float* __restrict__ ts,
               const float* __restrict__ W,
               const float* __restrict__ bias,
               float* __restrict__ out, int T)
{
    __shared__ float smem[EOFFF + NP_ * 33];   // 64 KB ring + 16.5 KB E

    const int tid  = threadIdx.x;
    const int lane = tid & 63;
    const int wave = tid >> 6;       // 0..7
    const int mt   = wave & 3;       // M-tile: rows [32mt, 32mt+32)
    const int p    = wave >> 2;      // k-step parity (0/1)

    // 256-block XCD encoding (proven): panels are adjacent f's of one b
    const int d  = blockIdx.x;
    const int b  = (d & 7) | (((d >> 7) & 1) << 3);
    const int fp = (d >> 3) & 15;
    const float* __restrict__ tsb0 = ts + ((size_t)(b * F_ + 2 * fp) * NP_) * D_;
    const float* __restrict__ tsb1 = tsb0 + (size_t)NP_ * D_;

    // staging unit: thread owns row lr, fp32 span [lu*16, lu*16+16) of chunk
    const int lr = tid >> 2;         // 0..127
    const int lu = tid & 3;          // 0..3

    float4 st[3][4];                 // staged regs, 3 chunk-steps deep
    auto LOAD = [&](int g) {         // 4 coalesced dwordx4
        const float* src = (g < 8 ? tsb0 : tsb1)
                         + (size_t)lr * D_ + (g & 7) * KC + lu * 16;
#pragma unroll
        for (int i = 0; i < 4; ++i) st[g % 3][i] = ((const float4*)src)[i];
    };
    // cvt to bf16, write 2 swizzled b128 quads into ring slot g&3.
    // bf16 row = 128 B = 8 quads; quad q holds k [8q, 8q+8); XOR q^(row&7).
    auto WRITE = [&](int g) {
        Frag q0, q1;
        q0.u[0] = cvt_pk_bf16(st[g%3][0].x, st[g%3][0].y);
        q0.u[1] = cvt_pk_bf16(st[g%3][0].z, st[g%3][0].w);
        q0.u[2] = cvt_pk_bf16(st[g%3][1].x, st[g%3][1].y);
        q0.u[3] = cvt_pk_bf16(st[g%3][1].z, st[g%3][1].w);
        q1.u[0] = cvt_pk_bf16(st[g%3][2].x, st[g%3][2].y);
        q1.u[1] = cvt_pk_bf16(st[g%3][2].z, st[g%3][2].w);
        q1.u[2] = cvt_pk_bf16(st[g%3][3].x, st[g%3][3].y);
        q1.u[3] = cvt_pk_bf16(st[g%3][3].z, st[g%3][3].w);
        short8* slot = (short8*)(smem + (g & 3) * SLOTF);
        slot[lr * 8 + ((2 * lu)     ^ (lr & 7))] = q0.v;
        slot[lr * 8 + ((2 * lu + 1) ^ (lr & 7))] = q1.v;
    };

    // ---- B preload ONCE (shared by both panels): s = 4c + p + 2j
    const int e_b = lane & 31;
    const int kh  = lane >> 5;
    Frag bf[8][2];
    // start the A stream first, then B (overlaps)
    LOAD(0); SB;
    LOAD(1); LOAD(2); SB;
    {
        const float* wb = W + (size_t)e_b * D_ + kh * 8;
#pragma unroll
        for (int c = 0; c < 8; ++c)
#pragma unroll
            for (int j = 0; j < 2; ++j) {
                const int k = (4 * c + p + 2 * j) * 16;
                const float4 lo = *(const float4*)(wb + k);
                const float4 hi = *(const float4*)(wb + k + 4);
                bf[c][j].u[0] = cvt_pk_bf16(lo.x, lo.y);
                bf[c][j].u[1] = cvt_pk_bf16(lo.z, lo.w);
                bf[c][j].u[2] = cvt_pk_bf16(hi.x, hi.y);
                bf[c][j].u[3] = cvt_pk_bf16(hi.z, hi.w);
            }
    }
    SB;
    WRITE(0);
    BAR; SB;

    // A-read addressing: row ro = mt*32 + (lane&31); quad qq=(p+2j)*2+kh
    const int ro = mt * 32 + (lane & 31);

    auto COMPUTE = [&](int g, floatx16& acc) {
        const short8* slot = (const short8*)(smem + (g & 3) * SLOTF);
#pragma unroll
        for (int j = 0; j < 2; ++j) {
            const int qq = (p + 2 * j) * 2 + kh;
            Frag a; a.v = slot[ro * 8 + (qq ^ (ro & 7))];
            acc = __builtin_amdgcn_mfma_f32_32x32x16_bf16(a.v, bf[g & 7][j].v, acc, 0, 0, 0);
        }
    };

    floatx16 accA, accB;
#pragma unroll
    for (int r = 0; r < 16; ++r) { accA[r] = 0.f; accB[r] = 0.f; }

    const int TF = T * F_;
    const size_t halfoff = (size_t)B_ * TF;
    float* const E = smem + EOFFF;
    const int f0 = 2 * fp;
    const int QT = (2 * T + 3) / 4;

    // ---- 16 chunk-steps, one barrier each; panel-0 epilogue as phases g=8..13
#pragma unroll
    for (int g = 0; g < NCHT; ++g) {
        if (g + 1 < NCHT) WRITE(g + 1);   // slot (g+1)&3: last read compute(g-3)
        if (g + 3 < NCHT) LOAD(g + 3);    // 3 steps of load slack
        SB;
        BAR;                               // publishes chunk g+1; chunk g ready
        SB;

        if (g == 8) {                      // p0 partial write of panel-0 raw
            if (p == 0) {
#pragma unroll
                for (int r = 0; r < 16; ++r) {
                    const int rowl = (r & 3) + 8 * (r >> 2) + 4 * kh;
                    E[(mt * 32 + rowl) * 33 + e_b] = accA[r];
                }
            }
        } else if (g == 9) {               // p1: add + bias + exp FUSED
            if (p == 1) {
#pragma unroll
                for (int r = 0; r < 16; ++r) {
                    const int rowl = (r & 3) + 8 * (r >> 2) + 4 * kh;
                    float v = E[(mt * 32 + rowl) * 33 + e_b] + accA[r] + bias[e_b];
                    if (e_b >= P_) v = fmaxf(expf(v), 1e-6f);
                    E[(mt * 32 + rowl) * 33 + e_b] = v;
                }
            }
        } else if (g >= 10 && g <= 13) {   // gather quarters -> out[f0]
            const int gq = g - 10;
            const int hi = min((gq + 1) * QT, 2 * T);
            for (int item = gq * QT + tid; item < hi; item += 512) {
                const int half = (item >= T) ? 1 : 0;
                const int t    = item - half * T;
                const int nmax = min(NP_ - 1, t >> 3);
                const int nmin = (t > 8) ? ((t - 8) >> 3) : 0;
                float sum = 0.f;
                const int cnt = nmax - nmin + 1;
                for (int nn = nmin; nn <= nmax; ++nn)
                    sum += E[nn * 33 + (half << 4) + (t - (nn << 3))];
                const float r = (cnt > 0) ? sum / (float)cnt : 0.f;
                out[(size_t)half * halfoff + (size_t)b * TF + (size_t)t * F_ + f0] = r;
            }
        }

        if (g < 8) COMPUTE(g, accA);
        else       COMPUTE(g, accB);
    }

    // ---- panel-1 tail epilogue (fused add/bias/exp; 2 LDS passes)
    const int f1 = 2 * fp + 1;
    if (p == 0) {
#pragma unroll
        for (int r = 0; r < 16; ++r) {
            const int rowl = (r & 3) + 8 * (r >> 2) + 4 * kh;
            E[(mt * 32 + rowl) * 33 + e_b] = accB[r];
        }
    }
    BAR;
    if (p == 1) {
#pragma unroll
        for (int r = 0; r < 16; ++r) {
            const int rowl = (r & 3) + 8 * (r >> 2) + 4 * kh;
            float v = E[(mt * 32 + rowl) * 33 + e_b] + accB[r] + bias[e_b];
            if (e_b >= P_) v = fmaxf(expf(v), 1e-6f);
            E[(mt * 32 + rowl) * 33 + e_b] = v;
        }
    }
    BAR;
    for (int item = tid; item < 2 * T; item += 512) {
        const int half = (item >= T) ? 1 : 0;
        const int t    = item - half * T;
        const int nmax = min(NP_ - 1, t >> 3);
        const int nmin = (t > 8) ? ((t - 8) >> 3) : 0;
        float sum = 0.f;
        const int cnt = nmax - nmin + 1;
        for (int nn = nmin; nn <= nmax; ++nn)
            sum += E[nn * 33 + (half << 4) + (t - (nn << 3))];
        const float r = (cnt > 0) ? sum / (float)cnt : 0.f;
        out[(size_t)half * halfoff + (size_t)b * TF + (size_t)t * F_ + f1] = r;
    }
}

extern "C" void kernel_launch(void* const* d_in, const int* in_sizes, int n_in,
                              void* d_out, int out_size, void* d_ws, size_t ws_size,
                              hipStream_t stream)
{
    const float* ts   = (const float*)d_in[0];
    const float* W    = (const float*)d_in[1];
    const float* bias = (const float*)d_in[2];
    float* out = (float*)d_out;

    // T derived on host from out_size = 2 * B * T * F
    const int T = out_size / (2 * B_ * F_);

    dim3 grid(B_ * F_ / 2);   // 256 blocks: 1 per CU, 2 adjacent panels each
    dim3 block(512);
    pd_kernel<<<grid, block, 0, stream>>>(ts, W, bias, out, T);
}

// Round 19
// 35.838 us; speedup vs baseline: 1.3182x; 1.0099x over previous
//
#include <hip/hip_runtime.h>
#include <math.h>

// Problem constants (fixed by the reference)
#define B_    16
#define F_    32
#define NP_   128   // rows per (b,f) panel
#define D_    512
#define P_    16
#define NSL   16            // total slab-steps (2 panels x 8 slabs of 16 rows)
#define SLABF 4096          // float-units per slab LDS image (16 KB bf16)
#define E0OFF (4 * SLABF)   // ring = 4 slabs = 64 KB
#define E1OFF (E0OFF + NP_ * 33)

typedef __attribute__((ext_vector_type(8))) short  short8;   // 8 bf16
typedef __attribute__((ext_vector_type(4))) float  floatx4;  // 16x16 acc

union Frag { short8 v; unsigned int u[4]; };

__device__ inline unsigned int cvt_pk_bf16(float lo, float hi) {
    unsigned int r;
    asm volatile("v_cvt_pk_bf16_f32 %0, %1, %2" : "=v"(r) : "v"(lo), "v"(hi));
    return r;
}

#define SB  __builtin_amdgcn_sched_barrier(0)
#define BAR asm volatile("s_waitcnt lgkmcnt(0)\n\ts_barrier" ::: "memory")

// 256 blocks (1/CU) x 512 threads = 8 waves. R19: SEQUENTIAL-STREAM tiling.
// Chunk = slab of 16 COMPLETE rows (32 KB contiguous) instead of a K-slice
// of all 128 rows -> the block reads its 512 KB purely sequentially (tests
// the DRAM burst-length hypothesis: every prior round read 256B @ 2KB
// stride). One slab = one 16-row M-tile: wave pair (e-halves nt=0/1, owner
// mt == slab&3) computes the slab's FULL GEMM (16 k-steps, 16x16x32) ->
// C-tiles final, NO parity merge; bias/exp fused into the C-write.
// Reg-staging (R18 path), ring of 4 slab images, loads 3 steps ahead,
// one barrier per step; panel-0 gather folded into steps 9-12.
__global__ __launch_bounds__(512, 2)
void pd_kernel(const float* __restrict__ ts,
               const float* __restrict__ W,
               const float* __restrict__ bias,
               float* __restrict__ out, int T)
{
    __shared__ float smem[E1OFF + NP_ * 33];   // 64 KB ring + 2 E buffers

    const int tid  = threadIdx.x;
    const int lane = tid & 63;
    const int wave = tid >> 6;       // 0..7
    const int nt   = wave & 1;       // e-half: e in [16nt, 16nt+16)
    const int mt   = wave >> 1;      // slab owner: slabs s with (s&3)==mt

    // 256-block XCD encoding (proven): panels are adjacent f's of one b
    const int d  = blockIdx.x;
    const int b  = (d & 7) | (((d >> 7) & 1) << 3);
    const int fp = (d >> 3) & 15;
    const float* __restrict__ tsb0 = ts + ((size_t)(b * F_ + 2 * fp) * NP_) * D_;
    const float* __restrict__ tsb1 = tsb0 + (size_t)NP_ * D_;

    // slab staging: thread -> row lr (0..15), 16-float span lq (0..31).
    // Consecutive threads read consecutive 64B -> the whole 32 KB slab is
    // ONE contiguous region; slabs advance sequentially through the panel.
    const int lr = tid >> 5;
    const int lq = tid & 31;

    float4 st[3][4];                 // staged regs, 3 slab-steps deep
    auto LOAD = [&](int g) {
        const float* src = (g < 8 ? tsb0 : tsb1)
                         + ((size_t)((g & 7) * 16 + lr)) * D_ + lq * 16;
#pragma unroll
        for (int i = 0; i < 4; ++i) st[g % 3][i] = ((const float4*)src)[i];
    };
    // cvt 16 fp32 -> 16 bf16 -> 2 swizzled b128 quads into slab image g&3.
    // Slab image: [16 rows][64 quads]; quad q of row r stored at q^r
    // (r<16, bijective; read side uses the same XOR -> conflict-free).
    auto WRITE = [&](int g) {
        Frag q0, q1;
        q0.u[0] = cvt_pk_bf16(st[g%3][0].x, st[g%3][0].y);
        q0.u[1] = cvt_pk_bf16(st[g%3][0].z, st[g%3][0].w);
        q0.u[2] = cvt_pk_bf16(st[g%3][1].x, st[g%3][1].y);
        q0.u[3] = cvt_pk_bf16(st[g%3][1].z, st[g%3][1].w);
        q1.u[0] = cvt_pk_bf16(st[g%3][2].x, st[g%3][2].y);
        q1.u[1] = cvt_pk_bf16(st[g%3][2].z, st[g%3][2].w);
        q1.u[2] = cvt_pk_bf16(st[g%3][3].x, st[g%3][3].y);
        q1.u[3] = cvt_pk_bf16(st[g%3][3].z, st[g%3][3].w);
        short8* slab = (short8*)(smem + (g & 3) * SLABF);
        const int qw = lq * 2;
        slab[lr * 64 + ( qw      ^ lr)] = q0.v;
        slab[lr * 64 + ((qw + 1) ^ lr)] = q1.v;
    };

    // ---- prologue: stream first, B preload overlapped
    LOAD(0); SB;
    LOAD(1); LOAD(2); SB;

    // B preload: wave's e = nt*16 + (lane&15); k-half kg = lane>>4.
    // All 16 k-steps -> 64 VGPR (R12-verified 16x16x32 B layout).
    const int el = lane & 15;
    const int kg = lane >> 4;
    const int ef = nt * 16 + el;
    Frag bf[16];
    {
        const float* wb = W + (size_t)ef * D_ + kg * 8;
#pragma unroll
        for (int ks = 0; ks < 16; ++ks) {
            const float4 lo = *(const float4*)(wb + ks * 32);
            const float4 hi = *(const float4*)(wb + ks * 32 + 4);
            bf[ks].u[0] = cvt_pk_bf16(lo.x, lo.y);
            bf[ks].u[1] = cvt_pk_bf16(lo.z, lo.w);
            bf[ks].u[2] = cvt_pk_bf16(hi.x, hi.y);
            bf[ks].u[3] = cvt_pk_bf16(hi.z, hi.w);
        }
    }
    SB;
    WRITE(0);
    BAR; SB;

    const int TF = T * F_;
    const size_t halfoff = (size_t)B_ * TF;
    const int f0 = 2 * fp, f1 = 2 * fp + 1;
    const int QT = (2 * T + 3) / 4;

    auto GATHER = [&](const float* E, int f, int lo_i, int hi_i) {
        for (int item = lo_i + tid; item < hi_i; item += 512) {
            const int half = (item >= T) ? 1 : 0;
            const int t    = item - half * T;
            const int nmax = min(NP_ - 1, t >> 3);
            const int nmin = (t > 8) ? ((t - 8) >> 3) : 0;
            float sum = 0.f;
            const int cnt = nmax - nmin + 1;
            for (int nn = nmin; nn <= nmax; ++nn)
                sum += E[nn * 33 + (half << 4) + (t - (nn << 3))];
            const float r = (cnt > 0) ? sum / (float)cnt : 0.f;
            out[(size_t)half * halfoff + (size_t)b * TF + (size_t)t * F_ + f] = r;
        }
    };

    // ---- 16 slab-steps, one barrier each
#pragma unroll
    for (int g = 0; g < NSL; ++g) {
        if (g + 1 < NSL) WRITE(g + 1);   // slot (g+1)&3: last read slab g-3
        if (g + 3 < NSL) LOAD(g + 3);    // 3 steps of load slack
        SB;
        BAR;                              // publishes slab g+1; slab g ready
        SB;

        if (g >= 9 && g <= 12) {          // panel-0 gather quarters (E0 done
            const int gq = g - 9;         // at step 7 + barrier step 8)
            GATHER(smem + E0OFF, f0, gq * QT, min((gq + 1) * QT, 2 * T));
        }

        if ((g & 3) == mt) {              // this wave pair owns slab g
            const short8* slab = (const short8*)(smem + (g & 3) * SLABF);
            floatx4 a4;
#pragma unroll
            for (int r = 0; r < 4; ++r) a4[r] = 0.f;
#pragma unroll
            for (int ks = 0; ks < 16; ++ks) {
                Frag a;
                a.v = slab[el * 64 + ((ks * 4 + kg) ^ el)];
                a4 = __builtin_amdgcn_mfma_f32_16x16x32_bf16(a.v, bf[ks].v, a4, 0, 0, 0);
            }
            // C-tile is FINAL (no K-split) -> fused bias/exp, direct E write.
            // 16x16 C map (R12-verified): col=lane&15, row=kg*4+r.
            float* E = smem + (g < 8 ? E0OFF : E1OFF);
            const float bv = bias[ef];
#pragma unroll
            for (int r = 0; r < 4; ++r) {
                const int rowl = (g & 7) * 16 + kg * 4 + r;
                float v = a4[r] + bv;
                if (ef >= P_) v = fmaxf(expf(v), 1e-6f);   // wave-uniform
                E[rowl * 33 + ef] = v;
            }
        }
    }

    // ---- tail: panel-1 gather
    BAR;
    GATHER(smem + E1OFF, f1, 0, 2 * T);
}

extern "C" void kernel_launch(void* const* d_in, const int* in_sizes, int n_in,
                              void* d_out, int out_size, void* d_ws, size_t ws_size,
                              hipStream_t stream)
{
    const float* ts   = (const float*)d_in[0];
    const float* W    = (const float*)d_in[1];
    const float* bias = (const float*)d_in[2];
    float* out = (float*)d_out;

    // T derived on host from out_size = 2 * B * T * F
    const int T = out_size / (2 * B_ * F_);

    dim3 grid(B_ * F_ / 2);   // 256 blocks: 1 per CU, 2 adjacent panels each
    dim3 block(512);
    pd_kernel<<<grid, block, 0, stream>>>(ts, W, bias, out, T);
}